// Round 1
// baseline (640.096 us; speedup 1.0000x reference)
//
#include <hip/hip_runtime.h>

// ws layout:
//   [0, K*4)                    : uint32 hist[K]
//   [align256(K*4), +16)        : double accums[2]  {sum_smoothed, bits_sum}

__global__ void zero_kernel(unsigned* __restrict__ hist, int K, double* __restrict__ accums) {
    int i = blockIdx.x * blockDim.x + threadIdx.x;
    int stride = gridDim.x * blockDim.x;
    for (int k = i; k < K; k += stride) hist[k] = 0u;
    if (i == 0) { accums[0] = 0.0; accums[1] = 0.0; }
}

__global__ void hist_kernel(const int* __restrict__ idx, long long n,
                            unsigned* __restrict__ hist) {
    long long tid = (long long)blockIdx.x * blockDim.x + threadIdx.x;
    long long nthreads = (long long)gridDim.x * blockDim.x;
    long long n4 = n & ~3LL;
    for (long long i = tid * 4; i < n4; i += nthreads * 4) {
        int4 v = *reinterpret_cast<const int4*>(idx + i);
        atomicAdd(&hist[v.x], 1u);
        atomicAdd(&hist[v.y], 1u);
        atomicAdd(&hist[v.z], 1u);
        atomicAdd(&hist[v.w], 1u);
    }
    // tail (n not multiple of 4)
    long long rem = n - n4;
    if (tid < rem) atomicAdd(&hist[idx[n4 + tid]], 1u);
}

__device__ __forceinline__ double block_reduce_double(double v) {
    // wave64 butterfly then LDS across waves
    #pragma unroll
    for (int off = 32; off > 0; off >>= 1) v += __shfl_down(v, off, 64);
    __shared__ double ws_[16];
    int lane = threadIdx.x & 63;
    int wid  = threadIdx.x >> 6;
    if (lane == 0) ws_[wid] = v;
    __syncthreads();
    double t = 0.0;
    if (threadIdx.x == 0) {
        int nw = (blockDim.x + 63) >> 6;
        for (int w = 0; w < nw; ++w) t += ws_[w];
    }
    return t;  // valid only on thread 0
}

// SMOOTH = 1e-8
__global__ void sum_kernel(const float* __restrict__ sc, const unsigned* __restrict__ hist,
                           int K, double* __restrict__ accums) {
    int i = blockIdx.x * blockDim.x + threadIdx.x;
    int stride = gridDim.x * blockDim.x;
    double s = 0.0;
    for (int k = i; k < K; k += stride)
        s += (double)sc[k] + (double)hist[k] + 1e-8;
    double t = block_reduce_double(s);
    if (threadIdx.x == 0) atomicAdd(&accums[0], t);
}

__global__ void bits_kernel(const float* __restrict__ sc, const unsigned* __restrict__ hist,
                            int K, double* __restrict__ accums) {
    double inv_sum = 1.0 / accums[0];
    int i = blockIdx.x * blockDim.x + threadIdx.x;
    int stride = gridDim.x * blockDim.x;
    double b = 0.0;
    for (int k = i; k < K; k += stride) {
        unsigned h = hist[k];
        if (h) {
            double smoothed = (double)sc[k] + (double)h + 1e-8;
            float p = (float)(smoothed * inv_sum);
            p = fmaxf(p, 1e-10f);
            b += (double)h * (double)(-log2f(p));
        }
    }
    double t = block_reduce_double(b);
    if (threadIdx.x == 0) atomicAdd(&accums[1], t);
}

__global__ void finalize_kernel(const double* __restrict__ accums, float* __restrict__ out,
                                long long n) {
    if (threadIdx.x == 0 && blockIdx.x == 0)
        out[0] = (float)(accums[1] / (double)n);
}

extern "C" void kernel_launch(void* const* d_in, const int* in_sizes, int n_in,
                              void* d_out, int out_size, void* d_ws, size_t ws_size,
                              hipStream_t stream) {
    const int*   indices = (const int*)d_in[0];
    const float* sc      = (const float*)d_in[1];
    long long n = (long long)in_sizes[0];   // B*T = 16,777,216
    int K = in_sizes[1];                    // 65536

    unsigned* hist = (unsigned*)d_ws;
    size_t acc_off = ((size_t)K * 4 + 255) & ~(size_t)255;
    double* accums = (double*)((char*)d_ws + acc_off);
    float* out = (float*)d_out;

    zero_kernel<<<64, 256, 0, stream>>>(hist, K, accums);
    hist_kernel<<<2048, 256, 0, stream>>>(indices, n, hist);
    sum_kernel<<<256, 256, 0, stream>>>(sc, hist, K, accums);
    bits_kernel<<<256, 256, 0, stream>>>(sc, hist, K, accums);
    finalize_kernel<<<1, 64, 0, stream>>>(accums, out, n);
}